// Round 12
// baseline (229.510 us; speedup 1.0000x reference)
//
#include <hip/hip_runtime.h>
#include <hip/hip_bf16.h>
#include <cstdint>
#include <cstddef>

// ---------------------------------------------------------------------------
// Attention block on MI355X (gfx950), bf16 MFMA everywhere.
//   x = LN(seq); q,k,v = x@W{q,k,v}.T + b (q pre-scaled by 0.125*log2e)
//   s' = q.k (log2 domain); e = 2^s'; w = e^2/(e+e^mu) = rcp(t + emu*t^2),
//   t = 2^-s'.  P = w / rowsum(w); out = (P @ v, heads merged) @ Wo.T + bo
// Attn: 512-thr blocks (8 waves x 32 q-rows), launch_bounds(512,4) -> 128
// VGPR budget so BOTH kh score tiles stay live; flattened kh pipeline
// (QKT0,QKT1 -> SM0,SM1 -> PV0,PV1) lets PV0 MFMAs overlap SM1 trans ops.
// ---------------------------------------------------------------------------

typedef __bf16 bf16_t;
typedef __bf16 bf16x4 __attribute__((ext_vector_type(4)));
typedef __bf16 bf16x8 __attribute__((ext_vector_type(8)));
typedef float  f32x2  __attribute__((ext_vector_type(2)));
typedef float  f32x4  __attribute__((ext_vector_type(4)));
typedef float  f32x16 __attribute__((ext_vector_type(16)));
typedef unsigned u32x4 __attribute__((ext_vector_type(4)));

#define MFMA16(a, b, c) __builtin_amdgcn_mfma_f32_16x16x32_bf16((a), (b), (c), 0, 0, 0)
#define MFMA32(a, b, c) __builtin_amdgcn_mfma_f32_32x32x16_bf16((a), (b), (c), 0, 0, 0)

#if __has_builtin(__builtin_amdgcn_exp2f)
#define VEXP2(x) __builtin_amdgcn_exp2f(x)
#else
#define VEXP2(x) __expf((x) * 0.6931471805599453f)
#endif

// packed f32->bf16 (RTNE), dst.lo16=cvt(a), dst.hi16=cvt(b)  [r5-proven]
__device__ __forceinline__ unsigned cvtpk_bf16(float a, float b) {
  unsigned r;
  asm("v_cvt_pk_bf16_f32 %0, %1, %2" : "=v"(r) : "v"(a), "v"(b));
  return r;
}

// full cross-half swap between two registers (gfx950)  [r5-proven, volatile]
__device__ __forceinline__ void plane32_swap(unsigned& a, unsigned& b) {
  asm volatile("v_permlane32_swap_b32 %0, %1" : "+v"(a), "+v"(b));
}

__device__ __forceinline__ void gload16(void* lds, const void* g) {
  __builtin_amdgcn_global_load_lds(
      (__attribute__((address_space(1))) void*)(uintptr_t)g,
      (__attribute__((address_space(3))) void*)(uint32_t)(uintptr_t)lds,
      16, 0, 0);
}

// ---------------- weights fp32 -> bf16 (4 x 1M elements, packed) -----------
__global__ __launch_bounds__(256) void cvt_w_k(
    const float* __restrict__ s0, const float* __restrict__ s1,
    const float* __restrict__ s2, const float* __restrict__ s3,
    bf16_t* __restrict__ dst)
{
  const float* src = blockIdx.y == 0 ? s0 : blockIdx.y == 1 ? s1
                   : blockIdx.y == 2 ? s2 : s3;
  int i = blockIdx.x * 256 + threadIdx.x;
  float4 v = ((const float4*)src)[i];
  bf16x4 o = { (bf16_t)v.x, (bf16_t)v.y, (bf16_t)v.z, (bf16_t)v.w };
  *(bf16x4*)(dst + (((size_t)blockIdx.y) << 20) + (size_t)i * 4) = o;
}

// ---------------- LayerNorm (row = 1024 fp32) -> bf16 ----------------------
__global__ __launch_bounds__(256) void ln_k(
    const float* __restrict__ x, const float* __restrict__ gamma,
    const float* __restrict__ beta, bf16_t* __restrict__ out)
{
  int row = blockIdx.x;
  int tid = threadIdx.x;
  float4 v = ((const float4*)(x + (size_t)row * 1024))[tid];
  float s  = v.x + v.y + v.z + v.w;
  float ss = v.x * v.x + v.y * v.y + v.z * v.z + v.w * v.w;
#pragma unroll
  for (int m = 1; m < 64; m <<= 1) { s += __shfl_xor(s, m); ss += __shfl_xor(ss, m); }
  __shared__ float sh_s[4], sh_q[4];
  int w = tid >> 6;
  if ((tid & 63) == 0) { sh_s[w] = s; sh_q[w] = ss; }
  __syncthreads();
  s  = sh_s[0] + sh_s[1] + sh_s[2] + sh_s[3];
  ss = sh_q[0] + sh_q[1] + sh_q[2] + sh_q[3];
  float mean = s * (1.0f / 1024.0f);
  float var  = ss * (1.0f / 1024.0f) - mean * mean;
  float rstd = rsqrtf(var + 1e-6f);
  float4 gv = ((const float4*)gamma)[tid];
  float4 bv = ((const float4*)beta)[tid];
  bf16x4 o = { (bf16_t)((v.x - mean) * rstd * gv.x + bv.x),
               (bf16_t)((v.y - mean) * rstd * gv.y + bv.y),
               (bf16_t)((v.z - mean) * rstd * gv.z + bv.z),
               (bf16_t)((v.w - mean) * rstd * gv.w + bv.w) };
  *(bf16x4*)(out + (size_t)row * 1024 + tid * 4) = o;
}

// ---------------- NT GEMM: C[M,N] = A[M,K] * Bw[N,K]^T + bias --------------
__global__ __launch_bounds__(256) void gemm_bt(
    const bf16_t* __restrict__ A, const bf16_t* __restrict__ Bw,
    const float* __restrict__ b0, const float* __restrict__ b1,
    const float* __restrict__ b2,
    void* __restrict__ o0, void* __restrict__ o1, void* __restrict__ o2,
    int M, int N, int K, int fused)
{
  __shared__ __align__(16) bf16_t a_lds[2][128][32];
  __shared__ __align__(16) bf16_t b_lds[2][128][32];
  const int tid = threadIdx.x;
  const int l = tid & 63, w = tid >> 6;
  const int wr = w >> 1, wc = w & 1;
  const int m0 = blockIdx.y * 128, n0 = blockIdx.x * 128;
  const int lr = l & 15, lg = l >> 4;

  f32x4 acc[4][4] = {};

  const int srow = tid >> 2;
  const int scol = (tid & 3) * 8;
  const bf16_t* ag = A  + (size_t)(m0 + srow) * K + scol;
  const bf16_t* bg = Bw + (size_t)(n0 + srow) * K + scol;

  gload16((char*)a_lds[0] + tid * 16,        ag);
  gload16((char*)a_lds[0] + 4096 + tid * 16, ag + (size_t)64 * K);
  gload16((char*)b_lds[0] + tid * 16,        bg);
  gload16((char*)b_lds[0] + 4096 + tid * 16, bg + (size_t)64 * K);
  __syncthreads();

  int cur = 0;
  for (int k0 = 0; k0 < K; k0 += 32) {
    if (k0 + 32 < K) {
      gload16((char*)a_lds[cur ^ 1] + tid * 16,        ag + k0 + 32);
      gload16((char*)a_lds[cur ^ 1] + 4096 + tid * 16, ag + (size_t)64 * K + k0 + 32);
      gload16((char*)b_lds[cur ^ 1] + tid * 16,        bg + k0 + 32);
      gload16((char*)b_lds[cur ^ 1] + 4096 + tid * 16, bg + (size_t)64 * K + k0 + 32);
    }
    bf16x8 af[4], bf[4];
#pragma unroll
    for (int i = 0; i < 4; ++i) {
      af[i] = *(const bf16x8*)&a_lds[cur][wr * 64 + i * 16 + lr][lg * 8];
      bf[i] = *(const bf16x8*)&b_lds[cur][wc * 64 + i * 16 + lr][lg * 8];
    }
#pragma unroll
    for (int i = 0; i < 4; ++i)
#pragma unroll
      for (int j = 0; j < 4; ++j)
        acc[i][j] = MFMA16(af[i], bf[j], acc[i][j]);
    __syncthreads();
    cur ^= 1;
  }

  int matsel = fused ? (n0 >> 10) : 0;
  const float* bias = matsel == 0 ? b0 : matsel == 1 ? b1 : b2;
  float bs[4];
#pragma unroll
  for (int j = 0; j < 4; ++j) bs[j] = bias[(n0 + wc * 64 + j * 16 + lr) & 1023];

#pragma unroll
  for (int i = 0; i < 4; ++i) {
#pragma unroll
    for (int j = 0; j < 4; ++j) {
      if (fused && matsel == 2) {
        // V^T scatter: rows r are consecutive s -> one packed bf16x4 store
        int row0 = m0 + wr * 64 + i * 16 + lg * 4;
        int col  = n0 + wc * 64 + j * 16 + lr;
        int nn = col & 1023;
        int bb = row0 >> 11, s0 = row0 & 2047, hh = nn >> 6, d = nn & 63;
        bf16x4 pv;
#pragma unroll
        for (int r = 0; r < 4; ++r) pv[r] = (bf16_t)(acc[i][j][r] + bs[j]);
        *(bf16x4*)((bf16_t*)o2 + ((((size_t)bb * 16 + hh) * 64) + d) * 2048 + s0) = pv;
      } else {
#pragma unroll
        for (int r = 0; r < 4; ++r) {
          int row = m0 + wr * 64 + i * 16 + lg * 4 + r;
          int col = n0 + wc * 64 + j * 16 + lr;
          float v = acc[i][j][r] + bs[j];
          if (!fused) {
            ((float*)o0)[(size_t)row * N + col] = v;
          } else {
            int nn = col & 1023;
            int bb = row >> 11, s = row & 2047, hh = nn >> 6, d = nn & 63;
            bf16_t* o = matsel ? (bf16_t*)o1 : (bf16_t*)o0;
            // fold 1/sqrt(hd) * log2(e) into q -> scores arrive in log2 domain
            if (matsel == 0) v *= 0.18033688011112042f;
            o[((((size_t)bb * 16 + hh) * 2048 + s) << 6) + d] = (bf16_t)v;
          }
        }
      }
    }
  }
}

// ---------------- fused attention (32x32 MFMA, in-register P) --------------
// flat grid 512 (XCD-swizzled), 512 thr = 8 waves x 32 q-rows = 256 q-rows.
// launch_bounds(512,4): 4 waves/SIMD guaranteed, 128 VGPR budget -> both kh
// score tiles live; flattened pipeline so PV(kh0) overlaps softmax(kh1).
__global__ __launch_bounds__(512, 4) void attn_k(
    const bf16_t* __restrict__ q, const bf16_t* __restrict__ k,
    const bf16_t* __restrict__ vT, const float* __restrict__ mu_p,
    bf16_t* __restrict__ out)
{
  const int S = 2048;
  int hw = blockIdx.x;
  int vid = (hw & 7) * 64 + (hw >> 3);    // 8 XCD chunks of 64; 8 blocks/bh
  int qt = vid & 7;                       // q-tile of 256 rows
  int bh = vid >> 3;
  int h = bh & 15, b = bh >> 4;

  const bf16_t* qb = q  + ((size_t)bh * S + qt * 256) * 64;
  const char* kbase = (const char*)(k  + (size_t)bh * S * 64);
  const char* vbase = (const char*)(vT + (size_t)bh * 64 * S);
  const float emu = __expf(mu_p[0]);      // e^mu (natural)

  __shared__ __align__(16) bf16_t k_lds[2][64][64];   // 16 KB
  __shared__ __align__(16) bf16_t v_lds[2][64][64];   // 16 KB

  const int tid = threadIdx.x, l = tid & 63, w = tid >> 6;  // w in 0..7
  const int l31 = l & 31, hi = l >> 5;
  const int swzr = (l31 & 7) << 4;        // row&7 XOR slot (row = *32k + l31)

  // Q fragments: lane holds Q[q=w*32+l31][hd=16ch+8hi+j]
  bf16x8 qf[4];
#pragma unroll
  for (int ch = 0; ch < 4; ++ch)
    qf[ch] = *(const bf16x8*)(qb + (size_t)(w * 32 + l31) * 64 + ch * 16 + hi * 8);

  // staging: 512 thr x 16B = 8 KB = one whole K (or V) tile per call
  const int srow = tid >> 3;                        // 0..63
  const int ssw  = ((tid & 7) * 16) ^ ((srow & 7) << 4);
  const int koff = srow * 128 + ssw;                // +t*8192
  const int voff = srow * 4096 + ssw;               // +t*128

  f32x16 oAcc[2] = {};                    // [dfrag]
  float rs0 = 0.f, rs1 = 0.f, rs2 = 0.f, rs3 = 0.f;

  gload16((char*)k_lds[0] + tid * 16, kbase + koff);
  gload16((char*)v_lds[0] + tid * 16, vbase + voff);
  __syncthreads();

#pragma unroll 2
  for (int t = 0; t < 32; ++t) {
    const int cur = t & 1;                 // constant after unroll-by-2
    if (t + 1 < 32) {
      gload16((char*)k_lds[cur ^ 1] + tid * 16, kbase + koff + (t + 1) * 8192);
      gload16((char*)v_lds[cur ^ 1] + tid * 16, vbase + voff + (t + 1) * 128);
    }

    // ---- QK^T for BOTH key halves (sc0, sc1 both stay live) ----
    f32x16 sc0 = {}, sc1 = {};
    __builtin_amdgcn_s_setprio(1);
#pragma unroll
    for (int ch = 0; ch < 4; ++ch) {
      bf16x8 kf0 = *(const bf16x8*)((const char*)k_lds[cur]
                     + (l31) * 128 + ((ch * 32 + hi * 16) ^ swzr));
      sc0 = MFMA32(kf0, qf[ch], sc0);
      bf16x8 kf1 = *(const bf16x8*)((const char*)k_lds[cur]
                     + (32 + l31) * 128 + ((ch * 32 + hi * 16) ^ swzr));
      sc1 = MFMA32(kf1, qf[ch], sc1);
    }
    __builtin_amdgcn_s_setprio(0);

    // ---- softmax both halves (trans pipe); Montgomery pair-inverse ----
    unsigned U0[8], U1[8];
#pragma unroll
    for (int m = 0; m < 8; ++m) {
      float t0 = VEXP2(-sc0[2 * m]);
      float t1 = VEXP2(-sc0[2 * m + 1]);
      float d0 = fmaf(emu * t0, t0, t0);
      float d1 = fmaf(emu * t1, t1, t1);
      float inv = __builtin_amdgcn_rcpf(d0 * d1);
      float w0 = inv * d1;
      float w1 = inv * d0;
      rs0 += w0; rs1 += w1;
      U0[m] = cvtpk_bf16(w0, w1);
    }
#pragma unroll
    for (int m = 0; m < 8; ++m) {
      float t0 = VEXP2(-sc1[2 * m]);
      float t1 = VEXP2(-sc1[2 * m + 1]);
      float d0 = fmaf(emu * t0, t0, t0);
      float d1 = fmaf(emu * t1, t1, t1);
      float inv = __builtin_amdgcn_rcpf(d0 * d1);
      float w0 = inv * d1;
      float w1 = inv * d0;
      rs2 += w0; rs3 += w1;
      U1[m] = cvtpk_bf16(w0, w1);
    }
    plane32_swap(U0[0], U0[2]);
    plane32_swap(U0[1], U0[3]);
    plane32_swap(U0[4], U0[6]);
    plane32_swap(U0[5], U0[7]);
    plane32_swap(U1[0], U1[2]);
    plane32_swap(U1[1], U1[3]);
    plane32_swap(U1[4], U1[6]);
    plane32_swap(U1[5], U1[7]);

    // ---- PV both halves (MFMA pipe; independent of SM of other half) ----
    __builtin_amdgcn_s_setprio(1);
#pragma unroll
    for (int cc = 0; cc < 2; ++cc) {
      u32x4 uu0 = { U0[cc * 4 + 0], U0[cc * 4 + 1], U0[cc * 4 + 2], U0[cc * 4 + 3] };
      bf16x8 pa0 = __builtin_bit_cast(bf16x8, uu0);
      int kcol0 = cc * 32 + hi * 16;
      u32x4 uu1 = { U1[cc * 4 + 0], U1[cc * 4 + 1], U1[cc * 4 + 2], U1[cc * 4 + 3] };
      bf16x8 pa1 = __builtin_bit_cast(bf16x8, uu1);
      int kcol1 = 64 + cc * 32 + hi * 16;
#pragma unroll
      for (int df = 0; df < 2; ++df) {
        bf16x8 vf0 = *(const bf16x8*)((const char*)v_lds[cur]
                       + (df * 32 + l31) * 128 + (kcol0 ^ swzr));
        oAcc[df] = MFMA32(pa0, vf0, oAcc[df]);
        bf16x8 vf1 = *(const bf16x8*)((const char*)v_lds[cur]
                       + (df * 32 + l31) * 128 + (kcol1 ^ swzr));
        oAcc[df] = MFMA32(pa1, vf1, oAcc[df]);
      }
    }
    __builtin_amdgcn_s_setprio(0);
    __syncthreads();
  }

  // row sums: lane holds partial for q = l31; lanes l and l+32 complete the row
  float rs = (rs0 + rs1) + (rs2 + rs3);
  rs += __shfl_xor(rs, 32);
  float rinv = __builtin_amdgcn_rcpf(rs);

#pragma unroll
  for (int r = 0; r < 16; ++r) {
    int q_loc = (r & 3) + 8 * (r >> 2) + 4 * hi;
    float ro = __shfl(rinv, q_loc);
    size_t row = (size_t)b * 2048 + qt * 256 + w * 32 + q_loc;
#pragma unroll
    for (int df = 0; df < 2; ++df) {
      out[row * 1024 + h * 64 + df * 32 + l31] = (bf16_t)(oAcc[df][r] * ro);
    }
  }
}

// ---------------------------------------------------------------------------
extern "C" void kernel_launch(void* const* d_in, const int* in_sizes, int n_in,
                              void* d_out, int out_size, void* d_ws, size_t ws_size,
                              hipStream_t stream) {
  const float* seq = (const float*)d_in[0];
  const float* g   = (const float*)d_in[1];
  const float* be  = (const float*)d_in[2];
  const float* Wq  = (const float*)d_in[3];
  const float* bq  = (const float*)d_in[4];
  const float* Wk  = (const float*)d_in[5];
  const float* bk  = (const float*)d_in[6];
  const float* Wv  = (const float*)d_in[7];
  const float* bv  = (const float*)d_in[8];
  const float* Wo  = (const float*)d_in[9];
  const float* bo  = (const float*)d_in[10];
  const float* mu  = (const float*)d_in[11];

  char* ws = (char*)d_ws;
  bf16_t* xb   = (bf16_t*)ws;  ws += (size_t)8192 * 1024 * 2;
  bf16_t* wAll = (bf16_t*)ws;  ws += (size_t)4 * 1024 * 1024 * 2;
  bf16_t* qb   = (bf16_t*)ws;  ws += (size_t)8192 * 1024 * 2;
  bf16_t* kbuf = (bf16_t*)ws;  ws += (size_t)8192 * 1024 * 2;
  bf16_t* vtb  = (bf16_t*)ws;  ws += (size_t)8192 * 1024 * 2;
  bf16_t* ab   = (bf16_t*)ws;  ws += (size_t)8192 * 1024 * 2;
  bf16_t* wqkv = wAll;
  bf16_t* wob  = wAll + (size_t)3 * 1024 * 1024;

  dim3 blk(256);
  cvt_w_k<<<dim3(1024, 4), blk, 0, stream>>>(Wq, Wk, Wv, Wo, wAll);
  ln_k<<<dim3(8192), blk, 0, stream>>>(seq, g, be, xb);
  gemm_bt<<<dim3(24, 64), blk, 0, stream>>>(xb, wqkv, bq, bk, bv,
                                            qb, kbuf, vtb, 8192, 3072, 1024, 1);
  attn_k<<<dim3(512), dim3(512), 0, stream>>>(qb, kbuf, vtb, mu, ab);
  gemm_bt<<<dim3(8, 64), blk, 0, stream>>>(ab, wob, bo, nullptr, nullptr,
                                           d_out, nullptr, nullptr, 8192, 1024, 1024, 0);
}

// Round 13
// 207.994 us; speedup vs baseline: 1.1034x; 1.1034x over previous
//
#include <hip/hip_runtime.h>
#include <hip/hip_bf16.h>
#include <cstdint>
#include <cstddef>

// ---------------------------------------------------------------------------
// Attention block on MI355X (gfx950), bf16 MFMA everywhere.
//   x = LN(seq); q,k,v = x@W{q,k,v}.T + b (q pre-scaled by 0.125*log2e)
//   s' = q.k (log2 domain); e = 2^s'; w = e^2/(e+e^mu) = rcp(t + emu*t^2),
//   t = 2^-s'.  P = w / rowsum(w); out = (P @ v, heads merged) @ Wo.T + bo
// Attn: r10-verified config — 512-thr blocks (8 waves x 32 q-rows), grid 512
// (2 blocks/CU, 16 waves/CU), 32x32x16 MFMA, in-register P (cvt_pk +
// permlane32_swap), Montgomery-batched rcp. No launch-bounds min-waves hint
// (r2/r12 lesson: hints trigger 64-VGPR + spill).
// ---------------------------------------------------------------------------

typedef __bf16 bf16_t;
typedef __bf16 bf16x4 __attribute__((ext_vector_type(4)));
typedef __bf16 bf16x8 __attribute__((ext_vector_type(8)));
typedef float  f32x4  __attribute__((ext_vector_type(4)));
typedef float  f32x16 __attribute__((ext_vector_type(16)));
typedef unsigned u32x4 __attribute__((ext_vector_type(4)));

#define MFMA16(a, b, c) __builtin_amdgcn_mfma_f32_16x16x32_bf16((a), (b), (c), 0, 0, 0)
#define MFMA32(a, b, c) __builtin_amdgcn_mfma_f32_32x32x16_bf16((a), (b), (c), 0, 0, 0)

#if __has_builtin(__builtin_amdgcn_exp2f)
#define VEXP2(x) __builtin_amdgcn_exp2f(x)
#else
#define VEXP2(x) __expf((x) * 0.6931471805599453f)
#endif

// packed f32->bf16 (RTNE), dst.lo16=cvt(a), dst.hi16=cvt(b)  [r5-proven]
__device__ __forceinline__ unsigned cvtpk_bf16(float a, float b) {
  unsigned r;
  asm("v_cvt_pk_bf16_f32 %0, %1, %2" : "=v"(r) : "v"(a), "v"(b));
  return r;
}

// full cross-half swap between two registers (gfx950)  [r5-proven, volatile]
__device__ __forceinline__ void plane32_swap(unsigned& a, unsigned& b) {
  asm volatile("v_permlane32_swap_b32 %0, %1" : "+v"(a), "+v"(b));
}

__device__ __forceinline__ void gload16(void* lds, const void* g) {
  __builtin_amdgcn_global_load_lds(
      (__attribute__((address_space(1))) void*)(uintptr_t)g,
      (__attribute__((address_space(3))) void*)(uint32_t)(uintptr_t)lds,
      16, 0, 0);
}

// ---------------- fused prep: weights fp32->bf16  +  LayerNorm -------------
// grid 12288: blocks 0..4095 convert the 4 weight matrices (1024 blocks each),
// blocks 4096..12287 LayerNorm one row each. Branch is block-uniform.
__global__ __launch_bounds__(256) void prep_k(
    const float* __restrict__ s0, const float* __restrict__ s1,
    const float* __restrict__ s2, const float* __restrict__ s3,
    bf16_t* __restrict__ wdst,
    const float* __restrict__ x, const float* __restrict__ gamma,
    const float* __restrict__ beta, bf16_t* __restrict__ xout)
{
  int bid = blockIdx.x;
  int tid = threadIdx.x;
  if (bid < 4096) {
    int part = bid >> 10;
    const float* src = part == 0 ? s0 : part == 1 ? s1 : part == 2 ? s2 : s3;
    int i = (bid & 1023) * 256 + tid;
    float4 v = ((const float4*)src)[i];
    bf16x4 o = { (bf16_t)v.x, (bf16_t)v.y, (bf16_t)v.z, (bf16_t)v.w };
    *(bf16x4*)(wdst + (((size_t)part) << 20) + (size_t)i * 4) = o;
  } else {
    int row = bid - 4096;
    float4 v = ((const float4*)(x + (size_t)row * 1024))[tid];
    float s  = v.x + v.y + v.z + v.w;
    float ss = v.x * v.x + v.y * v.y + v.z * v.z + v.w * v.w;
#pragma unroll
    for (int m = 1; m < 64; m <<= 1) { s += __shfl_xor(s, m); ss += __shfl_xor(ss, m); }
    __shared__ float sh_s[4], sh_q[4];
    int w = tid >> 6;
    if ((tid & 63) == 0) { sh_s[w] = s; sh_q[w] = ss; }
    __syncthreads();
    s  = sh_s[0] + sh_s[1] + sh_s[2] + sh_s[3];
    ss = sh_q[0] + sh_q[1] + sh_q[2] + sh_q[3];
    float mean = s * (1.0f / 1024.0f);
    float var  = ss * (1.0f / 1024.0f) - mean * mean;
    float rstd = rsqrtf(var + 1e-6f);
    float4 gv = ((const float4*)gamma)[tid];
    float4 bv = ((const float4*)beta)[tid];
    bf16x4 o = { (bf16_t)((v.x - mean) * rstd * gv.x + bv.x),
                 (bf16_t)((v.y - mean) * rstd * gv.y + bv.y),
                 (bf16_t)((v.z - mean) * rstd * gv.z + bv.z),
                 (bf16_t)((v.w - mean) * rstd * gv.w + bv.w) };
    *(bf16x4*)(xout + (size_t)row * 1024 + tid * 4) = o;
  }
}

// ---------------- NT GEMM: C[M,N] = A[M,K] * Bw[N,K]^T + bias --------------
__global__ __launch_bounds__(256) void gemm_bt(
    const bf16_t* __restrict__ A, const bf16_t* __restrict__ Bw,
    const float* __restrict__ b0, const float* __restrict__ b1,
    const float* __restrict__ b2,
    void* __restrict__ o0, void* __restrict__ o1, void* __restrict__ o2,
    int M, int N, int K, int fused)
{
  __shared__ __align__(16) bf16_t a_lds[2][128][32];
  __shared__ __align__(16) bf16_t b_lds[2][128][32];
  const int tid = threadIdx.x;
  const int l = tid & 63, w = tid >> 6;
  const int wr = w >> 1, wc = w & 1;
  const int m0 = blockIdx.y * 128, n0 = blockIdx.x * 128;
  const int lr = l & 15, lg = l >> 4;

  f32x4 acc[4][4] = {};

  const int srow = tid >> 2;
  const int scol = (tid & 3) * 8;
  const bf16_t* ag = A  + (size_t)(m0 + srow) * K + scol;
  const bf16_t* bg = Bw + (size_t)(n0 + srow) * K + scol;

  gload16((char*)a_lds[0] + tid * 16,        ag);
  gload16((char*)a_lds[0] + 4096 + tid * 16, ag + (size_t)64 * K);
  gload16((char*)b_lds[0] + tid * 16,        bg);
  gload16((char*)b_lds[0] + 4096 + tid * 16, bg + (size_t)64 * K);
  __syncthreads();

  int cur = 0;
  for (int k0 = 0; k0 < K; k0 += 32) {
    if (k0 + 32 < K) {
      gload16((char*)a_lds[cur ^ 1] + tid * 16,        ag + k0 + 32);
      gload16((char*)a_lds[cur ^ 1] + 4096 + tid * 16, ag + (size_t)64 * K + k0 + 32);
      gload16((char*)b_lds[cur ^ 1] + tid * 16,        bg + k0 + 32);
      gload16((char*)b_lds[cur ^ 1] + 4096 + tid * 16, bg + (size_t)64 * K + k0 + 32);
    }
    bf16x8 af[4], bf[4];
#pragma unroll
    for (int i = 0; i < 4; ++i) {
      af[i] = *(const bf16x8*)&a_lds[cur][wr * 64 + i * 16 + lr][lg * 8];
      bf[i] = *(const bf16x8*)&b_lds[cur][wc * 64 + i * 16 + lr][lg * 8];
    }
#pragma unroll
    for (int i = 0; i < 4; ++i)
#pragma unroll
      for (int j = 0; j < 4; ++j)
        acc[i][j] = MFMA16(af[i], bf[j], acc[i][j]);
    __syncthreads();
    cur ^= 1;
  }

  int matsel = fused ? (n0 >> 10) : 0;
  const float* bias = matsel == 0 ? b0 : matsel == 1 ? b1 : b2;
  float bs[4];
#pragma unroll
  for (int j = 0; j < 4; ++j) bs[j] = bias[(n0 + wc * 64 + j * 16 + lr) & 1023];

#pragma unroll
  for (int i = 0; i < 4; ++i) {
#pragma unroll
    for (int j = 0; j < 4; ++j) {
      if (fused && matsel == 2) {
        // V^T scatter: rows r are consecutive s -> one packed bf16x4 store
        int row0 = m0 + wr * 64 + i * 16 + lg * 4;
        int col  = n0 + wc * 64 + j * 16 + lr;
        int nn = col & 1023;
        int bb = row0 >> 11, s0 = row0 & 2047, hh = nn >> 6, d = nn & 63;
        bf16x4 pv;
#pragma unroll
        for (int r = 0; r < 4; ++r) pv[r] = (bf16_t)(acc[i][j][r] + bs[j]);
        *(bf16x4*)((bf16_t*)o2 + ((((size_t)bb * 16 + hh) * 64) + d) * 2048 + s0) = pv;
      } else {
#pragma unroll
        for (int r = 0; r < 4; ++r) {
          int row = m0 + wr * 64 + i * 16 + lg * 4 + r;
          int col = n0 + wc * 64 + j * 16 + lr;
          float v = acc[i][j][r] + bs[j];
          if (!fused) {
            ((float*)o0)[(size_t)row * N + col] = v;
          } else {
            int nn = col & 1023;
            int bb = row >> 11, s = row & 2047, hh = nn >> 6, d = nn & 63;
            bf16_t* o = matsel ? (bf16_t*)o1 : (bf16_t*)o0;
            // fold 1/sqrt(hd) * log2(e) into q -> scores arrive in log2 domain
            if (matsel == 0) v *= 0.18033688011112042f;
            o[((((size_t)bb * 16 + hh) * 2048 + s) << 6) + d] = (bf16_t)v;
          }
        }
      }
    }
  }
}

// ---------------- fused attention (32x32 MFMA, in-register P) --------------
// flat grid 512 (XCD-swizzled), 512 thr = 8 waves x 32 q-rows = 256 q-rows.
// 2 blocks/CU (64 KB LDS) -> 16 waves/CU so waves at different phases overlap
// MFMA / trans / VALU pipes. Swapped QK^T on 32x32x16; in-register P.
// [r10-verified: 109 us, 64 VGPR, no spill]
__global__ __launch_bounds__(512) void attn_k(
    const bf16_t* __restrict__ q, const bf16_t* __restrict__ k,
    const bf16_t* __restrict__ vT, const float* __restrict__ mu_p,
    bf16_t* __restrict__ out)
{
  const int S = 2048;
  int hw = blockIdx.x;
  int vid = (hw & 7) * 64 + (hw >> 3);    // 8 XCD chunks of 64; 8 blocks/bh
  int qt = vid & 7;                       // q-tile of 256 rows
  int bh = vid >> 3;
  int h = bh & 15, b = bh >> 4;

  const bf16_t* qb = q  + ((size_t)bh * S + qt * 256) * 64;
  const char* kbase = (const char*)(k  + (size_t)bh * S * 64);
  const char* vbase = (const char*)(vT + (size_t)bh * 64 * S);
  const float emu = __expf(mu_p[0]);      // e^mu (natural)

  __shared__ __align__(16) bf16_t k_lds[2][64][64];   // 16 KB
  __shared__ __align__(16) bf16_t v_lds[2][64][64];   // 16 KB

  const int tid = threadIdx.x, l = tid & 63, w = tid >> 6;  // w in 0..7
  const int l31 = l & 31, hi = l >> 5;
  const int swzr = (l31 & 7) << 4;        // row&7 XOR slot (row = *32k + l31)

  // Q fragments: lane holds Q[q=w*32+l31][hd=16ch+8hi+j]
  bf16x8 qf[4];
#pragma unroll
  for (int ch = 0; ch < 4; ++ch)
    qf[ch] = *(const bf16x8*)(qb + (size_t)(w * 32 + l31) * 64 + ch * 16 + hi * 8);

  // staging: 512 thr x 16B = 8 KB = one whole K (or V) tile per call
  const int srow = tid >> 3;                        // 0..63
  const int ssw  = ((tid & 7) * 16) ^ ((srow & 7) << 4);
  const int koff = srow * 128 + ssw;                // +t*8192
  const int voff = srow * 4096 + ssw;               // +t*128

  f32x16 oAcc[2] = {};                    // [dfrag]
  float rs0 = 0.f, rs1 = 0.f;

  gload16((char*)k_lds[0] + tid * 16, kbase + koff);
  gload16((char*)v_lds[0] + tid * 16, vbase + voff);
  __syncthreads();

#pragma unroll 2
  for (int t = 0; t < 32; ++t) {
    const int cur = t & 1;                 // constant after unroll-by-2
    if (t + 1 < 32) {
      gload16((char*)k_lds[cur ^ 1] + tid * 16, kbase + koff + (t + 1) * 8192);
      gload16((char*)v_lds[cur ^ 1] + tid * 16, vbase + voff + (t + 1) * 128);
    }

#pragma unroll
    for (int kh = 0; kh < 2; ++kh) {       // key half: k-local = kh*32 + ...
      // QK^T: S^T[32k x 32q] over hd=64 (4 chained MFMA)
      f32x16 sc = {};
      __builtin_amdgcn_s_setprio(1);
#pragma unroll
      for (int ch = 0; ch < 4; ++ch) {
        bf16x8 kf = *(const bf16x8*)((const char*)k_lds[cur]
                      + (kh * 32 + l31) * 128 + ((ch * 32 + hi * 16) ^ swzr));
        sc = MFMA32(kf, qf[ch], sc);
      }
      __builtin_amdgcn_s_setprio(0);

      // w = rcp(d), d = t + emu*t^2, t = 2^-s'.  Montgomery pair-inverse:
      // one v_rcp per TWO scores (inv=rcp(d0*d1); w0=inv*d1; w1=inv*d0).
      unsigned U[8];
#pragma unroll
      for (int m = 0; m < 8; ++m) {
        float t0 = VEXP2(-sc[2 * m]);
        float t1 = VEXP2(-sc[2 * m + 1]);
        float d0 = fmaf(emu * t0, t0, t0);
        float d1 = fmaf(emu * t1, t1, t1);
        float inv = __builtin_amdgcn_rcpf(d0 * d1);
        float w0 = inv * d1;
        float w1 = inv * d0;
        rs0 += w0; rs1 += w1;
        U[m] = cvtpk_bf16(w0, w1);
      }
      // cross-half exchange -> PV A-fragments
      plane32_swap(U[0], U[2]);
      plane32_swap(U[1], U[3]);
      plane32_swap(U[4], U[6]);
      plane32_swap(U[5], U[7]);
      // PV: chunks cc cover k-local = kh*32 + cc*16 + 8hi + j
      __builtin_amdgcn_s_setprio(1);
#pragma unroll
      for (int cc = 0; cc < 2; ++cc) {
        u32x4 uu = { U[cc * 4 + 0], U[cc * 4 + 1], U[cc * 4 + 2], U[cc * 4 + 3] };
        bf16x8 pa = __builtin_bit_cast(bf16x8, uu);
        int kcol = (kh * 2 + cc) * 32 + hi * 16;
#pragma unroll
        for (int df = 0; df < 2; ++df) {
          bf16x8 vf = *(const bf16x8*)((const char*)v_lds[cur]
                        + (df * 32 + l31) * 128 + (kcol ^ swzr));
          oAcc[df] = MFMA32(pa, vf, oAcc[df]);
        }
      }
      __builtin_amdgcn_s_setprio(0);
    }
    __syncthreads();
  }

  // row sums: lane holds partial for q = l31; lanes l and l+32 complete the row
  float rs = rs0 + rs1;
  rs += __shfl_xor(rs, 32);
  float rinv = __builtin_amdgcn_rcpf(rs);

#pragma unroll
  for (int r = 0; r < 16; ++r) {
    int q_loc = (r & 3) + 8 * (r >> 2) + 4 * hi;
    float ro = __shfl(rinv, q_loc);
    size_t row = (size_t)b * 2048 + qt * 256 + w * 32 + q_loc;
#pragma unroll
    for (int df = 0; df < 2; ++df) {
      out[row * 1024 + h * 64 + df * 32 + l31] = (bf16_t)(oAcc[df][r] * ro);
    }
  }
}

// ---------------------------------------------------------------------------
extern "C" void kernel_launch(void* const* d_in, const int* in_sizes, int n_in,
                              void* d_out, int out_size, void* d_ws, size_t ws_size,
                              hipStream_t stream) {
  const float* seq = (const float*)d_in[0];
  const float* g   = (const float*)d_in[1];
  const float* be  = (const float*)d_in[2];
  const float* Wq  = (const float*)d_in[3];
  const float* bq  = (const float*)d_in[4];
  const float* Wk  = (const float*)d_in[5];
  const float* bk  = (const float*)d_in[6];
  const float* Wv  = (const float*)d_in[7];
  const float* bv  = (const float*)d_in[8];
  const float* Wo  = (const float*)d_in[9];
  const float* bo  = (const float*)d_in[10];
  const float* mu  = (const float*)d_in[11];

  char* ws = (char*)d_ws;
  bf16_t* xb   = (bf16_t*)ws;  ws += (size_t)8192 * 1024 * 2;
  bf16_t* wAll = (bf16_t*)ws;  ws += (size_t)4 * 1024 * 1024 * 2;
  bf16_t* qb   = (bf16_t*)ws;  ws += (size_t)8192 * 1024 * 2;
  bf16_t* kbuf = (bf16_t*)ws;  ws += (size_t)8192 * 1024 * 2;
  bf16_t* vtb  = (bf16_t*)ws;  ws += (size_t)8192 * 1024 * 2;
  bf16_t* ab   = (bf16_t*)ws;  ws += (size_t)8192 * 1024 * 2;
  bf16_t* wqkv = wAll;
  bf16_t* wob  = wAll + (size_t)3 * 1024 * 1024;

  dim3 blk(256);
  prep_k<<<dim3(12288), blk, 0, stream>>>(Wq, Wk, Wv, Wo, wAll, seq, g, be, xb);
  gemm_bt<<<dim3(24, 64), blk, 0, stream>>>(xb, wqkv, bq, bk, bv,
                                            qb, kbuf, vtb, 8192, 3072, 1024, 1);
  attn_k<<<dim3(512), dim3(512), 0, stream>>>(qb, kbuf, vtb, mu, ab);
  gemm_bt<<<dim3(8, 64), blk, 0, stream>>>(ab, wob, bo, nullptr, nullptr,
                                           d_out, nullptr, nullptr, 8192, 1024, 1024, 0);
}